// Round 1
// baseline (563.526 us; speedup 1.0000x reference)
//
#include <hip/hip_runtime.h>
#include <stdint.h>

#define B_ 8
#define C_ 256
#define T_ 8192
#define G_ 128
#define QK_ 128
#define HID_ 512
#define NG_ 64   // T_/G_

typedef __attribute__((ext_vector_type(8))) short bf16x8;
typedef __attribute__((ext_vector_type(4))) short s16x4;
typedef __attribute__((ext_vector_type(4))) float f32x4;

__device__ __forceinline__ float b2f(short s){
  union { float f; unsigned u; } v; v.u = ((unsigned)(unsigned short)s) << 16; return v.f;
}
__device__ __forceinline__ short f2b(float f){
  union { float f; unsigned u; } v; v.f = f;
  unsigned r = (v.u + 0x7FFFu + ((v.u >> 16) & 1u)) >> 16;
  return (short)r;
}
__device__ __forceinline__ float silu_f(float x){ return x / (1.0f + expf(-x)); }
__device__ __forceinline__ float laplace_f(float x){
  // (1 + erf((x - sqrt(0.5)) / (sqrt(0.25*pi)*sqrt(2)))) * 0.5
  return 0.5f * (1.0f + erff((x - 0.70710678f) * 0.79788456f));
}
__device__ __forceinline__ f32x4 mfma16(bf16x8 a, bf16x8 b, f32x4 c){
  return __builtin_amdgcn_mfma_f32_16x16x32_bf16(a, b, c, 0, 0, 0);
}

// ---------------- weight prep: transpose + bf16 cast ----------------
__global__ void kw(const float* __restrict__ Wg, const float* __restrict__ Wv,
                   const float* __restrict__ Wqk, const float* __restrict__ Wo,
                   short* __restrict__ wgT, short* __restrict__ wvT,
                   short* __restrict__ wqkT, short* __restrict__ woT){
  int idx = blockIdx.x * 256 + threadIdx.x;
  int stride = gridDim.x * 256;
  // Wg/Wv [C][HID] -> [HID][C]
  for (int i = idx; i < C_ * HID_; i += stride){
    int c = i / HID_, e = i % HID_;
    wgT[e * C_ + c] = f2b(Wg[i]);
    wvT[e * C_ + c] = f2b(Wv[i]);
  }
  // Wqk [C][QK] -> [QK][C]
  for (int i = idx; i < C_ * QK_; i += stride){
    int c = i / QK_, d = i % QK_;
    wqkT[d * C_ + c] = f2b(Wqk[i]);
  }
  // Wo [HID][C] -> [C][HID]
  for (int i = idx; i < HID_ * C_; i += stride){
    int e = i / C_, c = i % C_;
    woT[c * HID_ + e] = f2b(Wo[i]);
  }
}

// ---------------- masks: all-zero fix, kpm ----------------
__global__ void k0(const float* __restrict__ masks, float* __restrict__ m_eff,
                   float* __restrict__ kpmf){
  int b = blockIdx.x, tid = threadIdx.x;
  __shared__ float red[256];
  float s = 0.f;
  for (int t = tid; t < T_; t += 256) s += masks[b * T_ + t];
  red[tid] = s; __syncthreads();
  for (int k = 128; k > 0; k >>= 1){ if (tid < k) red[tid] += red[tid + k]; __syncthreads(); }
  bool az = (red[0] == 0.0f);
  for (int t = tid; t < T_; t += 256){
    float m = az ? 1.0f : masks[b * T_ + t];
    m_eff[b * T_ + t] = m;
    kpmf[b * T_ + t] = (m == 0.0f) ? 1.0f : 0.0f;   // attention KEPT where mask==0 (source semantics)
  }
}

// ---------------- instance-norm stats ----------------
__global__ void k1(const float* __restrict__ q, float* __restrict__ mu, float* __restrict__ rstd){
  int bc = blockIdx.x, tid = threadIdx.x;
  const float* row = q + (size_t)bc * T_;
  float s = 0.f, ss = 0.f;
  for (int t = tid * 4; t < T_; t += 256 * 4){
    float4 v = *(const float4*)(row + t);
    s += v.x + v.y + v.z + v.w;
    ss += v.x * v.x + v.y * v.y + v.z * v.z + v.w * v.w;
  }
  __shared__ float r1[256], r2[256];
  r1[tid] = s; r2[tid] = ss; __syncthreads();
  for (int k = 128; k > 0; k >>= 1){
    if (tid < k){ r1[tid] += r1[tid + k]; r2[tid] += r2[tid + k]; }
    __syncthreads();
  }
  if (tid == 0){
    float m = r1[0] / (float)T_;
    float var = r2[0] / (float)T_ - m * m;
    mu[bc] = m;
    rstd[bc] = rsqrtf(var + 1e-5f);
  }
}

// ---------------- projections: gate, vh^T, 4 heads ----------------
__launch_bounds__(512)
__global__ void k2(const float* __restrict__ q, const float* __restrict__ v,
                   const float* __restrict__ mu, const float* __restrict__ rstd,
                   const short* __restrict__ wgT, const short* __restrict__ wvT,
                   const short* __restrict__ wqkT,
                   const float* __restrict__ bg, const float* __restrict__ bqk,
                   const float* __restrict__ bv,
                   const float* __restrict__ gamma, const float* __restrict__ beta,
                   const float* __restrict__ kpmf,
                   short* __restrict__ qqb, short* __restrict__ lqb,
                   short* __restrict__ qkkb, short* __restrict__ lkb,
                   short* __restrict__ gate, short* __restrict__ vhT){
  __shared__ __align__(16) short xlds[64 * 264];   // [64 t][264(c pad)]
  __shared__ __align__(16) short stage[9728];      // phase A: [64][136]; phase B: [128][72]
  int blk = blockIdx.x;
  int b = blk >> 7, tile = blk & 127;
  int t0 = tile * 64;
  int tid = threadIdx.x;
  int w = tid >> 6, lane = tid & 63, lr = lane & 15, lg = lane >> 4;
  int wm = w >> 2, wn = w & 3;
  int i0w = wm * 32, n0w = wn * 32;

  // ---- load x = normalized q^T tile ----
  {
    int cr = tid >> 4, tf = (tid & 15) * 4;
    #pragma unroll
    for (int it = 0; it < 8; ++it){
      int c = it * 32 + cr;
      float4 val = *(const float4*)(q + (size_t)(b * C_ + c) * T_ + t0 + tf);
      float m = mu[b * C_ + c], rs = rstd[b * C_ + c];
      xlds[(tf + 0) * 264 + c] = f2b((val.x - m) * rs);
      xlds[(tf + 1) * 264 + c] = f2b((val.y - m) * rs);
      xlds[(tf + 2) * 264 + c] = f2b((val.z - m) * rs);
      xlds[(tf + 3) * 264 + c] = f2b((val.w - m) * rs);
    }
  }
  __syncthreads();

  // ---- phase A: 4 gate passes + 1 qk pass ----
  for (int p = 0; p < 5; ++p){
    const short* wt = (p < 4) ? (wgT + p * 128 * C_) : wqkT;
    const float* bias = (p < 4) ? (bg + p * 128) : bqk;
    f32x4 acc[2][2];
    #pragma unroll
    for (int mi = 0; mi < 2; ++mi)
      #pragma unroll
      for (int ni = 0; ni < 2; ++ni) acc[mi][ni] = (f32x4){0.f, 0.f, 0.f, 0.f};
    #pragma unroll
    for (int ks = 0; ks < 8; ++ks){
      int kb = ks * 32 + lg * 8;
      bf16x8 a[2], bb[2];
      #pragma unroll
      for (int mi = 0; mi < 2; ++mi)
        a[mi] = *(const bf16x8*)&xlds[(i0w + mi * 16 + lr) * 264 + kb];
      #pragma unroll
      for (int ni = 0; ni < 2; ++ni)
        bb[ni] = *(const bf16x8*)(wt + (n0w + ni * 16 + lr) * C_ + kb);
      #pragma unroll
      for (int mi = 0; mi < 2; ++mi)
        #pragma unroll
        for (int ni = 0; ni < 2; ++ni)
          acc[mi][ni] = mfma16(a[mi], bb[ni], acc[mi][ni]);
    }
    if (p < 4){
      #pragma unroll
      for (int ni = 0; ni < 2; ++ni){
        float bvv = bias[n0w + ni * 16 + lr];
        #pragma unroll
        for (int mi = 0; mi < 2; ++mi)
          #pragma unroll
          for (int r = 0; r < 4; ++r){
            int i = i0w + mi * 16 + lg * 4 + r;
            stage[i * 136 + n0w + ni * 16 + lr] = f2b(silu_f(acc[mi][ni][r] + bvv));
          }
      }
      __syncthreads();
      int row = tid >> 3, l8 = tid & 7;
      short* dst = gate + (size_t)(b * T_ + t0 + row) * HID_ + p * 128 + l8 * 16;
      *(uint4*)(dst) = *(const uint4*)&stage[row * 136 + l8 * 16];
      *(uint4*)(dst + 8) = *(const uint4*)&stage[row * 136 + l8 * 16 + 8];
      __syncthreads();
    } else {
      // qk pass -> 4 pre-scaled heads
      float sreg[2][2][4];
      float kpv[2][4];
      #pragma unroll
      for (int ni = 0; ni < 2; ++ni){
        float bvv = bias[n0w + ni * 16 + lr];
        #pragma unroll
        for (int mi = 0; mi < 2; ++mi)
          #pragma unroll
          for (int r = 0; r < 4; ++r)
            sreg[mi][ni][r] = silu_f(acc[mi][ni][r] + bvv);
      }
      #pragma unroll
      for (int mi = 0; mi < 2; ++mi)
        #pragma unroll
        for (int r = 0; r < 4; ++r)
          kpv[mi][r] = kpmf[b * T_ + t0 + i0w + mi * 16 + lg * 4 + r];
      short* hd[4] = {qqb, lqb, qkkb, lkb};  // heads: 0=quad_q 1=lin_q 2=quad_k 3=lin_k
      for (int h = 0; h < 4; ++h){
        float gv[2], bvv2[2];
        #pragma unroll
        for (int ni = 0; ni < 2; ++ni){
          int n = n0w + ni * 16 + lr;
          gv[ni] = gamma[h * QK_ + n];
          bvv2[ni] = beta[h * QK_ + n];
        }
        #pragma unroll
        for (int mi = 0; mi < 2; ++mi)
          #pragma unroll
          for (int ni = 0; ni < 2; ++ni)
            #pragma unroll
            for (int r = 0; r < 4; ++r){
              float val = sreg[mi][ni][r] * gv[ni] + bvv2[ni];
              if (h == 3) val *= kpv[mi][r];   // lin_k masked (kept where mask==0)
              stage[(i0w + mi * 16 + lg * 4 + r) * 136 + n0w + ni * 16 + lr] = f2b(val);
            }
        __syncthreads();
        int row = tid >> 3, l8 = tid & 7;
        short* dst = hd[h] + (size_t)(b * T_ + t0 + row) * QK_ + l8 * 16;
        *(uint4*)(dst) = *(const uint4*)&stage[row * 136 + l8 * 16];
        *(uint4*)(dst + 8) = *(const uint4*)&stage[row * 136 + l8 * 16 + 8];
        __syncthreads();
      }
    }
  }

  // ---- phase B: v^T -> vh, stored transposed [B][HID][T] ----
  {
    int cr = tid >> 4, tf = (tid & 15) * 4;
    #pragma unroll
    for (int it = 0; it < 8; ++it){
      int c = it * 32 + cr;
      float4 val = *(const float4*)(v + (size_t)(b * C_ + c) * T_ + t0 + tf);
      xlds[(tf + 0) * 264 + c] = f2b(val.x);
      xlds[(tf + 1) * 264 + c] = f2b(val.y);
      xlds[(tf + 2) * 264 + c] = f2b(val.z);
      xlds[(tf + 3) * 264 + c] = f2b(val.w);
    }
  }
  __syncthreads();
  for (int p = 0; p < 4; ++p){
    const short* wt = wvT + p * 128 * C_;
    f32x4 acc[2][2];
    #pragma unroll
    for (int mi = 0; mi < 2; ++mi)
      #pragma unroll
      for (int ni = 0; ni < 2; ++ni) acc[mi][ni] = (f32x4){0.f, 0.f, 0.f, 0.f};
    #pragma unroll
    for (int ks = 0; ks < 8; ++ks){
      int kb = ks * 32 + lg * 8;
      bf16x8 a[2], bb[2];
      #pragma unroll
      for (int mi = 0; mi < 2; ++mi)
        a[mi] = *(const bf16x8*)&xlds[(i0w + mi * 16 + lr) * 264 + kb];
      #pragma unroll
      for (int ni = 0; ni < 2; ++ni)
        bb[ni] = *(const bf16x8*)(wt + (n0w + ni * 16 + lr) * C_ + kb);
      #pragma unroll
      for (int mi = 0; mi < 2; ++mi)
        #pragma unroll
        for (int ni = 0; ni < 2; ++ni)
          acc[mi][ni] = mfma16(a[mi], bb[ni], acc[mi][ni]);
    }
    // transposed stage: stage[n][72 i]
    #pragma unroll
    for (int ni = 0; ni < 2; ++ni){
      int n = n0w + ni * 16 + lr;
      float bvv = bv[p * 128 + n];
      #pragma unroll
      for (int mi = 0; mi < 2; ++mi){
        int ib = i0w + mi * 16 + lg * 4;
        s16x4 pk;
        #pragma unroll
        for (int r = 0; r < 4; ++r) pk[r] = f2b(silu_f(acc[mi][ni][r] + bvv));
        *(s16x4*)&stage[n * 72 + ib] = pk;
      }
    }
    __syncthreads();
    int row = tid >> 2, l4 = tid & 3;
    short* dst = vhT + (size_t)(b * HID_ + p * 128 + row) * T_ + t0 + l4 * 16;
    *(uint4*)(dst) = *(const uint4*)&stage[row * 72 + l4 * 16];
    *(uint4*)(dst + 8) = *(const uint4*)&stage[row * 72 + l4 * 16 + 8];
    __syncthreads();
  }
}

// ---------------- attention + gating + output GEMM ----------------
__launch_bounds__(512)
__global__ void k3(const short* __restrict__ qqb, const short* __restrict__ qkkb,
                   const short* __restrict__ lqb, const short* __restrict__ lkb,
                   const short* __restrict__ gate, const short* __restrict__ vhT,
                   const short* __restrict__ woT,
                   const float* __restrict__ kpmf, const float* __restrict__ m_eff,
                   const float* __restrict__ bo, float* __restrict__ out){
  __shared__ __align__(16) short slotA[128 * 136];  // linkv^T -> gate/y -> f32 out-stage
  __shared__ __align__(16) short slotB[128 * 136];  // attn
  __shared__ __align__(16) short slotC[128 * 136];  // lk^T [d][n]
  int blk = blockIdx.x;
  int b = blk >> 6, grp = blk & 63;
  int t0 = grp * G_;
  int tid = threadIdx.x;
  int w = tid >> 6, lane = tid & 63, lr = lane & 15, lg = lane >> 4;
  int wm = w >> 2, wn = w & 3;
  int i0w = wm * 64;    // m-base for GEMMs over query rows / e rows
  int j0w = wn * 32;    // GEMM2 n-base (keys)
  int e0w = wn * 32;    // GEMM5/7 n-base (hid chunk cols)
  int d0w = wn * 32;    // GEMM6 n-base (qk dim)
  int c0w = wn * 64;    // GEMM9 n-base (C cols)

  // ---- load lk^T into slotC ----
  {
    const short* src = lkb + (size_t)(b * T_ + t0) * QK_;
    int d4 = (tid & 31) * 4;
    #pragma unroll
    for (int rep = 0; rep < 8; ++rep){
      int n = rep * 16 + (tid >> 5);
      s16x4 vv = *(const s16x4*)(src + n * QK_ + d4);
      #pragma unroll
      for (int r = 0; r < 4; ++r) slotC[(d4 + r) * 136 + n] = vv[r];
    }
  }

  // ---- GEMM2: sim = qq . qkk^T / G -> laplace -> * kpm -> attn (slotB) ----
  {
    const short* qqp = qqb + (size_t)(b * T_ + t0) * QK_;
    const short* qkkp = qkkb + (size_t)(b * T_ + t0) * QK_;
    f32x4 sacc[4][2];
    #pragma unroll
    for (int mi = 0; mi < 4; ++mi)
      #pragma unroll
      for (int ni = 0; ni < 2; ++ni) sacc[mi][ni] = (f32x4){0.f, 0.f, 0.f, 0.f};
    #pragma unroll
    for (int ks = 0; ks < 4; ++ks){
      int kb = ks * 32 + lg * 8;
      bf16x8 a[4], bb[2];
      #pragma unroll
      for (int mi = 0; mi < 4; ++mi)
        a[mi] = *(const bf16x8*)(qqp + (i0w + mi * 16 + lr) * QK_ + kb);
      #pragma unroll
      for (int ni = 0; ni < 2; ++ni)
        bb[ni] = *(const bf16x8*)(qkkp + (j0w + ni * 16 + lr) * QK_ + kb);
      #pragma unroll
      for (int mi = 0; mi < 4; ++mi)
        #pragma unroll
        for (int ni = 0; ni < 2; ++ni)
          sacc[mi][ni] = mfma16(a[mi], bb[ni], sacc[mi][ni]);
    }
    #pragma unroll
    for (int ni = 0; ni < 2; ++ni){
      int j = j0w + ni * 16 + lr;
      float kp = kpmf[b * T_ + t0 + j];
      #pragma unroll
      for (int mi = 0; mi < 4; ++mi)
        #pragma unroll
        for (int r = 0; r < 4; ++r){
          int i = i0w + mi * 16 + lg * 4 + r;
          float s = sacc[mi][ni][r] * (1.0f / 128.0f);
          slotB[i * 136 + j] = f2b(laplace_f(s) * kp);
        }
    }
  }
  __syncthreads();

  f32x4 oacc[4][4];
  #pragma unroll
  for (int mi = 0; mi < 4; ++mi)
    #pragma unroll
    for (int ni = 0; ni < 4; ++ni) oacc[mi][ni] = (f32x4){0.f, 0.f, 0.f, 0.f};

  const short* lqp = lqb + (size_t)(b * T_ + t0) * QK_;

  for (int cN = 0; cN < 4; ++cN){
    int e0 = cN * 128;
    const short* vhp = vhT + (size_t)(b * HID_ + e0) * T_ + t0;  // [e][j], stride T_

    // GEMM5: quad = attn @ vh
    f32x4 pacc[4][2];
    #pragma unroll
    for (int mi = 0; mi < 4; ++mi)
      #pragma unroll
      for (int ni = 0; ni < 2; ++ni) pacc[mi][ni] = (f32x4){0.f, 0.f, 0.f, 0.f};
    #pragma unroll
    for (int ks = 0; ks < 4; ++ks){
      int jb = ks * 32 + lg * 8;
      bf16x8 a[4], bb[2];
      #pragma unroll
      for (int mi = 0; mi < 4; ++mi)
        a[mi] = *(const bf16x8*)&slotB[(i0w + mi * 16 + lr) * 136 + jb];
      #pragma unroll
      for (int ni = 0; ni < 2; ++ni)
        bb[ni] = *(const bf16x8*)(vhp + (size_t)(e0w + ni * 16 + lr) * T_ + jb);
      #pragma unroll
      for (int mi = 0; mi < 4; ++mi)
        #pragma unroll
        for (int ni = 0; ni < 2; ++ni)
          pacc[mi][ni] = mfma16(a[mi], bb[ni], pacc[mi][ni]);
    }

    // GEMM6: linkv^T[e][d] = sum_j vh[j][e] * lk[j][d] / T
    {
      f32x4 lacc[4][2];
      #pragma unroll
      for (int mi = 0; mi < 4; ++mi)
        #pragma unroll
        for (int ni = 0; ni < 2; ++ni) lacc[mi][ni] = (f32x4){0.f, 0.f, 0.f, 0.f};
      #pragma unroll
      for (int ks = 0; ks < 4; ++ks){
        int jb = ks * 32 + lg * 8;
        bf16x8 a[4], bb[2];
        #pragma unroll
        for (int mi = 0; mi < 4; ++mi)
          a[mi] = *(const bf16x8*)(vhp + (size_t)(i0w + mi * 16 + lr) * T_ + jb);
        #pragma unroll
        for (int ni = 0; ni < 2; ++ni)
          bb[ni] = *(const bf16x8*)&slotC[(d0w + ni * 16 + lr) * 136 + jb];
        #pragma unroll
        for (int mi = 0; mi < 4; ++mi)
          #pragma unroll
          for (int ni = 0; ni < 2; ++ni)
            lacc[mi][ni] = mfma16(a[mi], bb[ni], lacc[mi][ni]);
      }
      #pragma unroll
      for (int mi = 0; mi < 4; ++mi)
        #pragma unroll
        for (int ni = 0; ni < 2; ++ni){
          int d = d0w + ni * 16 + lr;
          #pragma unroll
          for (int r = 0; r < 4; ++r){
            int e = i0w + mi * 16 + lg * 4 + r;
            slotA[e * 136 + d] = f2b(lacc[mi][ni][r] * (1.0f / 8192.0f));
          }
        }
    }
    __syncthreads();

    // GEMM7: pacc += lq @ linkv
    #pragma unroll
    for (int ks = 0; ks < 4; ++ks){
      int db = ks * 32 + lg * 8;
      bf16x8 a[4], bb[2];
      #pragma unroll
      for (int mi = 0; mi < 4; ++mi)
        a[mi] = *(const bf16x8*)(lqp + (i0w + mi * 16 + lr) * QK_ + db);
      #pragma unroll
      for (int ni = 0; ni < 2; ++ni)
        bb[ni] = *(const bf16x8*)&slotA[(e0w + ni * 16 + lr) * 136 + db];
      #pragma unroll
      for (int mi = 0; mi < 4; ++mi)
        #pragma unroll
        for (int ni = 0; ni < 2; ++ni)
          pacc[mi][ni] = mfma16(a[mi], bb[ni], pacc[mi][ni]);
    }
    __syncthreads();

    // stage gate chunk into slotA
    {
      const short* gp = gate + (size_t)(b * T_ + t0) * HID_ + e0;
      int row = tid >> 2, l4 = tid & 3;
      #pragma unroll
      for (int jj = 0; jj < 4; ++jj)
        *(uint4*)&slotA[row * 136 + l4 * 32 + jj * 8] =
            *(const uint4*)(gp + (size_t)row * HID_ + l4 * 32 + jj * 8);
    }
    __syncthreads();

    // y = gate * (quad + lin), in place in slotA
    #pragma unroll
    for (int mi = 0; mi < 4; ++mi)
      #pragma unroll
      for (int ni = 0; ni < 2; ++ni){
        int e = e0w + ni * 16 + lr;
        #pragma unroll
        for (int r = 0; r < 4; ++r){
          int i = i0w + mi * 16 + lg * 4 + r;
          int idx = i * 136 + e;
          slotA[idx] = f2b(b2f(slotA[idx]) * pacc[mi][ni][r]);
        }
      }
    __syncthreads();

    // GEMM9: oacc += y @ Wo[chunk]
    #pragma unroll
    for (int ks = 0; ks < 4; ++ks){
      int eb = ks * 32 + lg * 8;
      bf16x8 a[4], bb[4];
      #pragma unroll
      for (int mi = 0; mi < 4; ++mi)
        a[mi] = *(const bf16x8*)&slotA[(i0w + mi * 16 + lr) * 136 + eb];
      #pragma unroll
      for (int ni = 0; ni < 4; ++ni)
        bb[ni] = *(const bf16x8*)(woT + (size_t)(c0w + ni * 16 + lr) * HID_ + e0 + eb);
      #pragma unroll
      for (int mi = 0; mi < 4; ++mi)
        #pragma unroll
        for (int ni = 0; ni < 4; ++ni)
          oacc[mi][ni] = mfma16(a[mi], bb[ni], oacc[mi][ni]);
    }
    __syncthreads();
  }

  // ---- epilogue: +bo, *masks, transposed coalesced store ----
  float* fstage = (float*)(void*)slotA;   // [64 c][132 i]
  for (int cp = 0; cp < 4; ++cp){
    if (wn == cp){
      #pragma unroll
      for (int mi = 0; mi < 4; ++mi)
        #pragma unroll
        for (int ni = 0; ni < 4; ++ni){
          int cc = ni * 16 + lr;
          int ib = i0w + mi * 16 + lg * 4;
          *(f32x4*)&fstage[cc * 132 + ib] = oacc[mi][ni];
        }
    }
    __syncthreads();
    int crow = tid >> 3, l8 = tid & 7;
    int c = cp * 64 + crow;
    float bov = bo[c];
    float* orow = out + (size_t)(b * C_ + c) * T_ + t0;
    const float* mrow = m_eff + (size_t)b * T_ + t0;
    #pragma unroll
    for (int jj = 0; jj < 4; ++jj){
      int toff = l8 * 16 + jj * 4;
      float4 a = *(const float4*)&fstage[crow * 132 + toff];
      float4 m = *(const float4*)(mrow + toff);
      float4 o;
      o.x = (a.x + bov) * m.x; o.y = (a.y + bov) * m.y;
      o.z = (a.z + bov) * m.z; o.w = (a.w + bov) * m.w;
      *(float4*)(orow + toff) = o;
    }
    __syncthreads();
  }
}

extern "C" void kernel_launch(void* const* d_in, const int* in_sizes, int n_in,
                              void* d_out, int out_size, void* d_ws, size_t ws_size,
                              hipStream_t stream) {
  const float* q     = (const float*)d_in[0];
  // d_in[1] = k : unused by the reference
  const float* v     = (const float*)d_in[2];
  const float* masks = (const float*)d_in[3];
  const float* Wg    = (const float*)d_in[4];
  const float* bg    = (const float*)d_in[5];
  const float* Wv    = (const float*)d_in[6];
  const float* bv    = (const float*)d_in[7];
  const float* Wqk   = (const float*)d_in[8];
  const float* bqk   = (const float*)d_in[9];
  const float* gamma = (const float*)d_in[10];
  const float* beta  = (const float*)d_in[11];
  const float* Wo    = (const float*)d_in[12];
  const float* bo    = (const float*)d_in[13];
  float* out = (float*)d_out;

  char* ws = (char*)d_ws;
  size_t o = 0;
  auto nxt = [&](size_t bytes) -> char* {
    char* p = ws + o;
    o += (bytes + 255) & ~(size_t)255;
    return p;
  };
  short* wgT   = (short*)nxt((size_t)HID_ * C_ * 2);
  short* wvT   = (short*)nxt((size_t)HID_ * C_ * 2);
  short* wqkT  = (short*)nxt((size_t)QK_ * C_ * 2);
  short* woT   = (short*)nxt((size_t)C_ * HID_ * 2);
  float* muW   = (float*)nxt((size_t)B_ * C_ * 4);
  float* rstdW = (float*)nxt((size_t)B_ * C_ * 4);
  float* m_eff = (float*)nxt((size_t)B_ * T_ * 4);
  float* kpmf  = (float*)nxt((size_t)B_ * T_ * 4);
  short* qqb   = (short*)nxt((size_t)B_ * T_ * QK_ * 2);
  short* lqb   = (short*)nxt((size_t)B_ * T_ * QK_ * 2);
  short* qkkb  = (short*)nxt((size_t)B_ * T_ * QK_ * 2);
  short* lkb   = (short*)nxt((size_t)B_ * T_ * QK_ * 2);
  short* gateW = (short*)nxt((size_t)B_ * T_ * HID_ * 2);
  short* vhT   = (short*)nxt((size_t)B_ * HID_ * T_ * 2);
  (void)in_sizes; (void)n_in; (void)out_size; (void)ws_size;  // needs ~203 MB of ws

  kw<<<dim3(512), dim3(256), 0, stream>>>(Wg, Wv, Wqk, Wo, wgT, wvT, wqkT, woT);
  k0<<<dim3(B_), dim3(256), 0, stream>>>(masks, m_eff, kpmf);
  k1<<<dim3(B_ * C_), dim3(256), 0, stream>>>(q, muW, rstdW);
  k2<<<dim3(B_ * (T_ / 64)), dim3(512), 0, stream>>>(q, v, muW, rstdW, wgT, wvT, wqkT,
                                                     bg, bqk, bv, gamma, beta, kpmf,
                                                     qqb, lqb, qkkb, lkb, gateW, vhT);
  k3<<<dim3(B_ * NG_), dim3(512), 0, stream>>>(qqb, qkkb, lqb, lkb, gateW, vhT, woT,
                                               kpmf, m_eff, bo, out);
}